// Round 1
// baseline (403.694 us; speedup 1.0000x reference)
//
#include <hip/hip_runtime.h>
#include <hip/hip_bf16.h>
#include <cstdint>
#include <cstddef>

#define DIM 4096
#define NB 16
#define NH 32
#define NKV 8
#define HD 128
#define PREFIX 8192
#define TOTALK (PREFIX + 1)
#define CHUNK 256
#define NCHUNK ((TOTALK + CHUNK - 1) / CHUNK)  // 33

// workspace layout (in floats)
#define WS_QKV 0                                   // [16][6144]  q|k_new|v_new
#define WS_ATT (WS_QKV + NB * 6144)                // [16][4096]  attn output
#define WS_ML  (WS_ATT + NB * DIM)                 // [16][8][33][4][2]
#define WS_OP  (WS_ML + NB * NKV * NCHUNK * 4 * 2) // [16][8][33][4][128]

// ---------------------------------------------------------------------------
// Batched GEMV: Y[b][row] = sum_d X[b][d] * W[row][d], B=16, D=4096.
// W is the concatenation of up to three row-major matrices (row boundaries
// b1, b2). Block = 128 threads = 2 waves; each wave owns 4 rows x 16 batches.
// ---------------------------------------------------------------------------
__global__ __launch_bounds__(128) void gemv16(
    const float* __restrict__ W0, const float* __restrict__ W1,
    const float* __restrict__ W2, int b1, int b2,
    const float* __restrict__ X, float* __restrict__ Y,
    int y_stride, int scale_rows, float scale) {
  __shared__ float xs[NB][512];
  const int tid = threadIdx.x;
  const int wave = tid >> 6, lane = tid & 63;
  const int row_base = blockIdx.x * 8 + wave * 4;

  const float* Wp;
  if (row_base < b1)       Wp = W0 + (size_t)row_base * DIM;
  else if (row_base < b2)  Wp = W1 + (size_t)(row_base - b1) * DIM;
  else                     Wp = W2 + (size_t)(row_base - b2) * DIM;

  float acc[4][NB];
#pragma unroll
  for (int r = 0; r < 4; ++r)
#pragma unroll
    for (int b = 0; b < NB; ++b) acc[r][b] = 0.0f;

  for (int k0 = 0; k0 < DIM; k0 += 512) {
    __syncthreads();
    // stage x[:, k0:k0+512] -> LDS (2048 float4, 128 threads -> 16 each)
#pragma unroll
    for (int i = 0; i < 16; ++i) {
      int idx = tid + i * 128;
      int b = idx >> 7, c = idx & 127;
      ((float4*)&xs[b][0])[c] = ((const float4*)(X + (size_t)b * DIM + k0))[c];
    }
    __syncthreads();
#pragma unroll
    for (int ii = 0; ii < 2; ++ii) {
      const int d = ii * 256 + lane * 4;
      float4 w4[4];
#pragma unroll
      for (int r = 0; r < 4; ++r)
        w4[r] = *(const float4*)(Wp + (size_t)r * DIM + k0 + d);
#pragma unroll
      for (int b = 0; b < NB; ++b) {
        float4 x4 = *(const float4*)&xs[b][d];
#pragma unroll
        for (int r = 0; r < 4; ++r)
          acc[r][b] += w4[r].x * x4.x + w4[r].y * x4.y +
                       w4[r].z * x4.z + w4[r].w * x4.w;
      }
    }
  }

  // reduce each of the 64 (row,batch) partials across the 64 lanes
#pragma unroll
  for (int r = 0; r < 4; ++r)
#pragma unroll
    for (int b = 0; b < NB; ++b) {
      float v = acc[r][b];
#pragma unroll
      for (int m = 1; m < 64; m <<= 1) v += __shfl_xor(v, m);
      acc[r][b] = v;
    }
  const int rsel = lane >> 4, bsel = lane & 15;
  float v = 0.0f;
#pragma unroll
  for (int r = 0; r < 4; ++r)
#pragma unroll
    for (int b = 0; b < NB; ++b)
      if (r == rsel && b == bsel) v = acc[r][b];  // compile-time indices only
  const int row = row_base + rsel;
  if (row < scale_rows) v *= scale;
  Y[(size_t)bsel * y_stride + row] = v;
}

// ---------------------------------------------------------------------------
// Flash-decoding partial: one block per (b, kv-head g, 256-key chunk).
// 256 threads = 4 waves; wave w scores keys [w*64, w*64+64) of the chunk for
// all 4 q-heads of the group, then wave h does softmax+PV for head h.
// ---------------------------------------------------------------------------
__global__ __launch_bounds__(256) void attn_partial(
    const float* __restrict__ K, const float* __restrict__ V,
    const float* __restrict__ qkv, float* __restrict__ opart,
    float* __restrict__ mlpart) {
  __shared__ float sc[4 * CHUNK];  // scores, then p = exp(s-m)
  const int tid = threadIdx.x, wave = tid >> 6, lane = tid & 63;
  const int s = lane & 7, grp = lane >> 3;
  const int bid = blockIdx.x;
  const int chunk = bid % NCHUNK;
  const int bg = bid / NCHUNK;
  const int g = bg & 7, b = bg >> 3;

  // q fragments in registers: lane covers dims {s*4 + j*32 + 0..3}
  float4 qreg[4][4];
#pragma unroll
  for (int hh = 0; hh < 4; ++hh)
#pragma unroll
    for (int j = 0; j < 4; ++j)
      qreg[hh][j] = *(const float4*)(qkv + (size_t)b * 6144 +
                                     (g * 4 + hh) * HD + j * 32 + s * 4);

  const int kbase = chunk * CHUNK + wave * 64;
  const float* knew = qkv + (size_t)b * 6144 + 4096 + g * HD;
  const float* kcache = K + ((size_t)b * PREFIX * NKV + g) * HD;
  const bool full = (kbase + 64 <= PREFIX);

#pragma unroll 2
  for (int it = 0; it < 8; ++it) {
    const int key = kbase + it * 8 + grp;
    const float* krow;
    if (full) {
      krow = kcache + (size_t)key * (NKV * HD);
    } else {
      const int keyc = key < PREFIX ? key : PREFIX;
      krow = (keyc < PREFIX) ? kcache + (size_t)keyc * (NKV * HD) : knew;
    }
    float p0 = 0, p1 = 0, p2 = 0, p3 = 0;
#pragma unroll
    for (int j = 0; j < 4; ++j) {
      float4 k4 = *(const float4*)(krow + j * 32 + s * 4);
      p0 += qreg[0][j].x * k4.x + qreg[0][j].y * k4.y + qreg[0][j].z * k4.z + qreg[0][j].w * k4.w;
      p1 += qreg[1][j].x * k4.x + qreg[1][j].y * k4.y + qreg[1][j].z * k4.z + qreg[1][j].w * k4.w;
      p2 += qreg[2][j].x * k4.x + qreg[2][j].y * k4.y + qreg[2][j].z * k4.z + qreg[2][j].w * k4.w;
      p3 += qreg[3][j].x * k4.x + qreg[3][j].y * k4.y + qreg[3][j].z * k4.z + qreg[3][j].w * k4.w;
    }
    // reduce across the 8 lanes sharing this key
#pragma unroll
    for (int mk = 1; mk < 8; mk <<= 1) {
      p0 += __shfl_xor(p0, mk);
      p1 += __shfl_xor(p1, mk);
      p2 += __shfl_xor(p2, mk);
      p3 += __shfl_xor(p3, mk);
    }
    if (!full && key >= TOTALK) { p0 = p1 = p2 = p3 = -1e30f; }
    if (s == 0) {
      const int kl = wave * 64 + it * 8 + grp;
      sc[0 * CHUNK + kl] = p0;
      sc[1 * CHUNK + kl] = p1;
      sc[2 * CHUNK + kl] = p2;
      sc[3 * CHUNK + kl] = p3;
    }
  }
  __syncthreads();

  // per-head softmax over the 256 chunk scores; wave h <-> head h
  const int h = wave;
  float4 s4 = *(const float4*)&sc[h * CHUNK + lane * 4];
  float m = fmaxf(fmaxf(s4.x, s4.y), fmaxf(s4.z, s4.w));
#pragma unroll
  for (int mk = 1; mk < 64; mk <<= 1) m = fmaxf(m, __shfl_xor(m, mk));
  float4 p4;
  p4.x = __expf(s4.x - m);
  p4.y = __expf(s4.y - m);
  p4.z = __expf(s4.z - m);
  p4.w = __expf(s4.w - m);
  float lsum = p4.x + p4.y + p4.z + p4.w;
#pragma unroll
  for (int mk = 1; mk < 64; mk <<= 1) lsum += __shfl_xor(lsum, mk);
  *(float4*)&sc[h * CHUNK + lane * 4] = p4;
  __syncthreads();  // make this wave's p writes visible across its own lanes

  // PV: thread (wave=h, lane) accumulates dims d0, d0+1 over 256 keys
  float accx = 0, accy = 0;
  const int d0 = lane * 2;
  const float* vcache = V + ((size_t)b * PREFIX * NKV + g) * HD + d0;
  const float* vnew = qkv + (size_t)b * 6144 + 5120 + g * HD + d0;
  if (chunk * CHUNK + CHUNK <= PREFIX) {
    const float* vp = vcache + (size_t)(chunk * CHUNK) * (NKV * HD);
#pragma unroll 8
    for (int k = 0; k < CHUNK; ++k) {
      const float p = sc[h * CHUNK + k];
      float2 v2 = *(const float2*)(vp + (size_t)k * (NKV * HD));
      accx += p * v2.x;
      accy += p * v2.y;
    }
  } else {
#pragma unroll 4
    for (int k = 0; k < CHUNK; ++k) {
      const int key = chunk * CHUNK + k;
      const float p = sc[h * CHUNK + k];
      const float* vp = (key < PREFIX) ? vcache + (size_t)key * (NKV * HD) : vnew;
      float2 v2 = *(const float2*)vp;
      accx += p * v2.x;
      accy += p * v2.y;
    }
  }
  const size_t pidx = (((size_t)(b * NKV + g)) * NCHUNK + chunk) * 4 + h;
  *(float2*)(opart + pidx * HD + d0) = make_float2(accx, accy);
  if (lane == 0) {
    mlpart[pidx * 2 + 0] = m;
    mlpart[pidx * 2 + 1] = lsum;
  }
}

// ---------------------------------------------------------------------------
// Combine the 33 chunk-partials per (b, global head). One wave per (b,h).
// ---------------------------------------------------------------------------
__global__ __launch_bounds__(64) void combine(
    const float* __restrict__ opart, const float* __restrict__ mlpart,
    float* __restrict__ aout) {
  const int bh = blockIdx.x;  // b*32 + hg
  const int hg = bh & 31, b = bh >> 5;
  const int g = hg >> 2, hh = hg & 3;
  const int lane = threadIdx.x;
  const size_t base = ((size_t)(b * NKV + g)) * NCHUNK;

  float M = -1e30f;
  for (int c = 0; c < NCHUNK; ++c)
    M = fmaxf(M, mlpart[((base + c) * 4 + hh) * 2]);

  float L = 0, ax = 0, ay = 0;
  for (int c = 0; c < NCHUNK; ++c) {
    const size_t pidx = (base + c) * 4 + hh;
    const float mc = mlpart[pidx * 2 + 0];
    const float lc = mlpart[pidx * 2 + 1];
    const float w = __expf(mc - M);
    L += lc * w;
    float2 o2 = *(const float2*)(opart + pidx * HD + lane * 2);
    ax += w * o2.x;
    ay += w * o2.y;
  }
  const float inv = 1.0f / L;
  aout[(size_t)b * DIM + hg * HD + lane * 2 + 0] = ax * inv;
  aout[(size_t)b * DIM + hg * HD + lane * 2 + 1] = ay * inv;
}

// ---------------------------------------------------------------------------
extern "C" void kernel_launch(void* const* d_in, const int* in_sizes, int n_in,
                              void* d_out, int out_size, void* d_ws,
                              size_t ws_size, hipStream_t stream) {
  const float* x  = (const float*)d_in[0];
  const float* ck = (const float*)d_in[1];
  const float* cv = (const float*)d_in[2];
  const float* wq = (const float*)d_in[3];
  const float* wk = (const float*)d_in[4];
  const float* wv = (const float*)d_in[5];
  const float* wo = (const float*)d_in[6];
  float* out = (float*)d_out;
  float* ws = (float*)d_ws;

  float* qkv = ws + WS_QKV;
  float* att = ws + WS_ATT;
  float* ml  = ws + WS_ML;
  float* op  = ws + WS_OP;

  const float scale = 0.08838834764831845f;  // 1/sqrt(128)

  // 1) fused q/k_new/v_new projection (6144 rows, 8 rows per 128-thr block)
  gemv16<<<768, 128, 0, stream>>>(wq, wk, wv, 4096, 5120, x, qkv, 6144, 4096,
                                  scale);
  // 2) flash-decoding partials over 33 key-chunks
  attn_partial<<<NB * NKV * NCHUNK, 256, 0, stream>>>(ck, cv, qkv, op, ml);
  // 3) merge partials
  combine<<<NB * NH, 64, 0, stream>>>(op, ml, att);
  // 4) output projection (4096 rows)
  gemv16<<<512, 128, 0, stream>>>(wo, wo, wo, 4096, 4096, att, out, 4096, 0,
                                  1.0f);
}

// Round 2
// 353.395 us; speedup vs baseline: 1.1423x; 1.1423x over previous
//
#include <hip/hip_runtime.h>
#include <hip/hip_bf16.h>
#include <cstdint>
#include <cstddef>

#define DIM 4096
#define NB 16
#define NH 32
#define NKV 8
#define HD 128
#define PREFIX 8192
#define TOTALK (PREFIX + 1)
#define CHUNK 512
#define NCHUNK ((TOTALK + CHUNK - 1) / CHUNK)  // 17

// workspace layout (in floats)
#define WS_QKV 0                                   // [16][6144]  q|k_new|v_new
#define WS_ATT (WS_QKV + NB * 6144)                // [16][4096]  attn output
#define WS_ML  (WS_ATT + NB * DIM)                 // [16][8][17][4][2]
#define WS_OP  (WS_ML + NB * NKV * NCHUNK * 4 * 2) // [16][8][17][4][128]

// ---------------------------------------------------------------------------
// Batched GEMV: Y[b][row] = sum_d X[b][d] * W[row][d], B=16, D=4096.
// W is the concatenation of up to three row-major matrices (row boundaries
// b1, b2). Block = 256 threads = 4 waves; each wave owns 4 rows x 16 batches;
// block owns 16 rows, so x is staged once per 16 rows (vs 8 before).
// ---------------------------------------------------------------------------
__global__ __launch_bounds__(256) void gemv16(
    const float* __restrict__ W0, const float* __restrict__ W1,
    const float* __restrict__ W2, int b1, int b2,
    const float* __restrict__ X, float* __restrict__ Y,
    int y_stride, int scale_rows, float scale) {
  __shared__ float xs[NB][512];
  const int tid = threadIdx.x;
  const int wave = tid >> 6, lane = tid & 63;
  const int row_base = blockIdx.x * 16 + wave * 4;

  const float* Wp;
  if (row_base < b1)       Wp = W0 + (size_t)row_base * DIM;
  else if (row_base < b2)  Wp = W1 + (size_t)(row_base - b1) * DIM;
  else                     Wp = W2 + (size_t)(row_base - b2) * DIM;

  float acc[4][NB];
#pragma unroll
  for (int r = 0; r < 4; ++r)
#pragma unroll
    for (int b = 0; b < NB; ++b) acc[r][b] = 0.0f;

  for (int k0 = 0; k0 < DIM; k0 += 512) {
    __syncthreads();
    // stage x[:, k0:k0+512] -> LDS (2048 float4, 256 threads -> 8 each)
#pragma unroll
    for (int i = 0; i < 8; ++i) {
      int idx = tid + i * 256;
      int b = idx >> 7, c = idx & 127;
      ((float4*)&xs[b][0])[c] = ((const float4*)(X + (size_t)b * DIM + k0))[c];
    }
    __syncthreads();
#pragma unroll
    for (int ii = 0; ii < 2; ++ii) {
      const int d = ii * 256 + lane * 4;
      float4 w4[4];
#pragma unroll
      for (int r = 0; r < 4; ++r)
        w4[r] = *(const float4*)(Wp + (size_t)r * DIM + k0 + d);
#pragma unroll
      for (int b = 0; b < NB; ++b) {
        float4 x4 = *(const float4*)&xs[b][d];
#pragma unroll
        for (int r = 0; r < 4; ++r)
          acc[r][b] += w4[r].x * x4.x + w4[r].y * x4.y +
                       w4[r].z * x4.z + w4[r].w * x4.w;
      }
    }
  }

  // reduce each of the 64 (row,batch) partials across the 64 lanes
#pragma unroll
  for (int r = 0; r < 4; ++r)
#pragma unroll
    for (int b = 0; b < NB; ++b) {
      float v = acc[r][b];
#pragma unroll
      for (int m = 1; m < 64; m <<= 1) v += __shfl_xor(v, m);
      acc[r][b] = v;
    }
  const int rsel = lane >> 4, bsel = lane & 15;
  float v = 0.0f;
#pragma unroll
  for (int r = 0; r < 4; ++r)
#pragma unroll
    for (int b = 0; b < NB; ++b)
      if (r == rsel && b == bsel) v = acc[r][b];  // compile-time indices only
  const int row = row_base + rsel;
  if (row < scale_rows) v *= scale;
  Y[(size_t)bsel * y_stride + row] = v;
}

// ---------------------------------------------------------------------------
// Flash-decoding partial: one block per (b, kv-head g, 512-key chunk).
// 256 threads = 4 waves; wave w scores keys [w*128, w*128+128) of the chunk
// for all 4 q-heads of the group, then wave h does softmax+PV for head h.
// ---------------------------------------------------------------------------
__global__ __launch_bounds__(256) void attn_partial(
    const float* __restrict__ K, const float* __restrict__ V,
    const float* __restrict__ qkv, float* __restrict__ opart,
    float* __restrict__ mlpart) {
  __shared__ float sc[4 * CHUNK];  // scores, then p = exp(s-m)
  const int tid = threadIdx.x, wave = tid >> 6, lane = tid & 63;
  const int s = lane & 7, grp = lane >> 3;
  const int bid = blockIdx.x;
  const int chunk = bid % NCHUNK;
  const int bg = bid / NCHUNK;
  const int g = bg & 7, b = bg >> 3;

  // q fragments in registers: lane covers dims {s*4 + j*32 + 0..3}
  float4 qreg[4][4];
#pragma unroll
  for (int hh = 0; hh < 4; ++hh)
#pragma unroll
    for (int j = 0; j < 4; ++j)
      qreg[hh][j] = *(const float4*)(qkv + (size_t)b * 6144 +
                                     (g * 4 + hh) * HD + j * 32 + s * 4);

  const int kbase = chunk * CHUNK + wave * 128;
  const float* knew = qkv + (size_t)b * 6144 + 4096 + g * HD;
  const float* kcache = K + ((size_t)b * PREFIX * NKV + g) * HD;

  if (kbase >= TOTALK) {
    // whole wave masked: no loads
#pragma unroll
    for (int hh = 0; hh < 4; ++hh) {
      sc[hh * CHUNK + wave * 128 + lane] = -1e30f;
      sc[hh * CHUNK + wave * 128 + 64 + lane] = -1e30f;
    }
  } else {
    const bool full = (kbase + 128 <= PREFIX);
#pragma unroll 2
    for (int it = 0; it < 16; ++it) {
      const int key = kbase + it * 8 + grp;
      const float* krow;
      if (full) {
        krow = kcache + (size_t)key * (NKV * HD);
      } else {
        const int keyc = key < PREFIX ? key : PREFIX;
        krow = (keyc < PREFIX) ? kcache + (size_t)keyc * (NKV * HD) : knew;
      }
      float p0 = 0, p1 = 0, p2 = 0, p3 = 0;
#pragma unroll
      for (int j = 0; j < 4; ++j) {
        float4 k4 = *(const float4*)(krow + j * 32 + s * 4);
        p0 += qreg[0][j].x * k4.x + qreg[0][j].y * k4.y + qreg[0][j].z * k4.z + qreg[0][j].w * k4.w;
        p1 += qreg[1][j].x * k4.x + qreg[1][j].y * k4.y + qreg[1][j].z * k4.z + qreg[1][j].w * k4.w;
        p2 += qreg[2][j].x * k4.x + qreg[2][j].y * k4.y + qreg[2][j].z * k4.z + qreg[2][j].w * k4.w;
        p3 += qreg[3][j].x * k4.x + qreg[3][j].y * k4.y + qreg[3][j].z * k4.z + qreg[3][j].w * k4.w;
      }
      // reduce across the 8 lanes sharing this key
#pragma unroll
      for (int mk = 1; mk < 8; mk <<= 1) {
        p0 += __shfl_xor(p0, mk);
        p1 += __shfl_xor(p1, mk);
        p2 += __shfl_xor(p2, mk);
        p3 += __shfl_xor(p3, mk);
      }
      if (!full && key >= TOTALK) { p0 = p1 = p2 = p3 = -1e30f; }
      if (s == 0) {
        const int kl = wave * 128 + it * 8 + grp;
        sc[0 * CHUNK + kl] = p0;
        sc[1 * CHUNK + kl] = p1;
        sc[2 * CHUNK + kl] = p2;
        sc[3 * CHUNK + kl] = p3;
      }
    }
  }
  __syncthreads();

  // per-head softmax over the 512 chunk scores; wave h <-> head h
  const int h = wave;
  float* sch = &sc[h * CHUNK];
  float4 sa = *(const float4*)&sch[lane * 4];
  float4 sb = *(const float4*)&sch[256 + lane * 4];
  float m = fmaxf(fmaxf(fmaxf(sa.x, sa.y), fmaxf(sa.z, sa.w)),
                  fmaxf(fmaxf(sb.x, sb.y), fmaxf(sb.z, sb.w)));
#pragma unroll
  for (int mk = 1; mk < 64; mk <<= 1) m = fmaxf(m, __shfl_xor(m, mk));
  float4 pa, pb;
  pa.x = __expf(sa.x - m); pa.y = __expf(sa.y - m);
  pa.z = __expf(sa.z - m); pa.w = __expf(sa.w - m);
  pb.x = __expf(sb.x - m); pb.y = __expf(sb.y - m);
  pb.z = __expf(sb.z - m); pb.w = __expf(sb.w - m);
  float lsum = pa.x + pa.y + pa.z + pa.w + pb.x + pb.y + pb.z + pb.w;
#pragma unroll
  for (int mk = 1; mk < 64; mk <<= 1) lsum += __shfl_xor(lsum, mk);
  *(float4*)&sch[lane * 4] = pa;
  *(float4*)&sch[256 + lane * 4] = pb;
  __syncthreads();

  // PV: half-wave kpar handles keys of parity kpar; lane covers 4 dims
  const int dgrp = lane & 31, kpar = lane >> 5;
  const int d0 = dgrp * 4;
  float4 acc = make_float4(0.f, 0.f, 0.f, 0.f);
  const float* vcache = V + ((size_t)b * PREFIX * NKV + g) * HD + d0;
  const float* vnew = qkv + (size_t)b * 6144 + 5120 + g * HD + d0;
  if (chunk * CHUNK + CHUNK <= PREFIX) {
    const float* vp = vcache + (size_t)(chunk * CHUNK + kpar) * (NKV * HD);
#pragma unroll 8
    for (int kk = 0; kk < CHUNK; kk += 2) {
      const float p = sch[kk + kpar];
      float4 v4 = *(const float4*)(vp + (size_t)kk * (NKV * HD));
      acc.x += p * v4.x; acc.y += p * v4.y;
      acc.z += p * v4.z; acc.w += p * v4.w;
    }
  } else {
#pragma unroll 4
    for (int kk = 0; kk < CHUNK; kk += 2) {
      const int key = chunk * CHUNK + kk + kpar;
      const float p = sch[kk + kpar];
      const float* vp = (key < PREFIX) ? vcache + (size_t)key * (NKV * HD) : vnew;
      float4 v4 = *(const float4*)vp;
      acc.x += p * v4.x; acc.y += p * v4.y;
      acc.z += p * v4.z; acc.w += p * v4.w;
    }
  }
  // merge the two key-parity halves
  acc.x += __shfl_xor(acc.x, 32);
  acc.y += __shfl_xor(acc.y, 32);
  acc.z += __shfl_xor(acc.z, 32);
  acc.w += __shfl_xor(acc.w, 32);
  const size_t pidx = (((size_t)(b * NKV + g)) * NCHUNK + chunk) * 4 + h;
  if (lane < 32) *(float4*)(opart + pidx * HD + d0) = acc;
  if (lane == 0) {
    mlpart[pidx * 2 + 0] = m;
    mlpart[pidx * 2 + 1] = lsum;
  }
}

// ---------------------------------------------------------------------------
// Combine the 17 chunk-partials per (b, global head). One wave per (b,h).
// ---------------------------------------------------------------------------
__global__ __launch_bounds__(64) void combine(
    const float* __restrict__ opart, const float* __restrict__ mlpart,
    float* __restrict__ aout) {
  const int bh = blockIdx.x;  // b*32 + hg
  const int hg = bh & 31, b = bh >> 5;
  const int g = hg >> 2, hh = hg & 3;
  const int lane = threadIdx.x;
  const size_t base = ((size_t)(b * NKV + g)) * NCHUNK;

  float M = -1e30f;
  for (int c = 0; c < NCHUNK; ++c)
    M = fmaxf(M, mlpart[((base + c) * 4 + hh) * 2]);

  float L = 0, ax = 0, ay = 0;
  for (int c = 0; c < NCHUNK; ++c) {
    const size_t pidx = (base + c) * 4 + hh;
    const float mc = mlpart[pidx * 2 + 0];
    const float lc = mlpart[pidx * 2 + 1];
    const float w = __expf(mc - M);
    L += lc * w;
    float2 o2 = *(const float2*)(opart + pidx * HD + lane * 2);
    ax += w * o2.x;
    ay += w * o2.y;
  }
  const float inv = 1.0f / L;
  aout[(size_t)b * DIM + hg * HD + lane * 2 + 0] = ax * inv;
  aout[(size_t)b * DIM + hg * HD + lane * 2 + 1] = ay * inv;
}

// ---------------------------------------------------------------------------
extern "C" void kernel_launch(void* const* d_in, const int* in_sizes, int n_in,
                              void* d_out, int out_size, void* d_ws,
                              size_t ws_size, hipStream_t stream) {
  const float* x  = (const float*)d_in[0];
  const float* ck = (const float*)d_in[1];
  const float* cv = (const float*)d_in[2];
  const float* wq = (const float*)d_in[3];
  const float* wk = (const float*)d_in[4];
  const float* wv = (const float*)d_in[5];
  const float* wo = (const float*)d_in[6];
  float* out = (float*)d_out;
  float* ws = (float*)d_ws;

  float* qkv = ws + WS_QKV;
  float* att = ws + WS_ATT;
  float* ml  = ws + WS_ML;
  float* op  = ws + WS_OP;

  const float scale = 0.08838834764831845f;  // 1/sqrt(128)

  // 1) fused q/k_new/v_new projection (6144 rows, 16 rows per 256-thr block)
  gemv16<<<384, 256, 0, stream>>>(wq, wk, wv, 4096, 5120, x, qkv, 6144, 4096,
                                  scale);
  // 2) flash-decoding partials over 17 key-chunks
  attn_partial<<<NB * NKV * NCHUNK, 256, 0, stream>>>(ck, cv, qkv, op, ml);
  // 3) merge partials
  combine<<<NB * NH, 64, 0, stream>>>(op, ml, att);
  // 4) output projection (4096 rows)
  gemv16<<<256, 256, 0, stream>>>(wo, wo, wo, 4096, 4096, att, out, 4096, 0,
                                  1.0f);
}

// Round 3
// 290.468 us; speedup vs baseline: 1.3898x; 1.2166x over previous
//
#include <hip/hip_runtime.h>
#include <hip/hip_bf16.h>
#include <cstdint>
#include <cstddef>

#define DIM 4096
#define NB 16
#define NH 32
#define NKV 8
#define HD 128
#define PREFIX 8192
#define CHUNK 1024
#define NCHUNK 8   // 8 x 1024 = PREFIX; the new token is folded into combine

// workspace layout (in floats)
#define WS_QKV 0                                   // [16][6144]  q|k_new|v_new
#define WS_ATT (WS_QKV + NB * 6144)                // [16][4096]  attn output
#define WS_ML  (WS_ATT + NB * DIM)                 // [16][8][8][4][2]
#define WS_OP  (WS_ML + NB * NKV * NCHUNK * 4 * 2) // [16][8][8][4][128]

// ---------------------------------------------------------------------------
// Batched GEMV: Y[b][row] = sum_d X[b][d] * W[row][d], B=16, D=4096.
// W = concat of up to three row-major matrices (boundaries b1,b2).
// NW waves per block; each wave owns 4 rows x 16 batches. x staged in two
// 2048-dim chunks (128 KB LDS) -> only 2 barrier pairs per block.
// ---------------------------------------------------------------------------
template <int NW>
__global__ __launch_bounds__(NW * 64) void gemv16(
    const float* __restrict__ W0, const float* __restrict__ W1,
    const float* __restrict__ W2, int b1, int b2,
    const float* __restrict__ X, float* __restrict__ Y,
    int y_stride, int scale_rows, float scale) {
  __shared__ float xs[NB][2048];  // 128 KB
  const int tid = threadIdx.x;
  const int wave = tid >> 6, lane = tid & 63;
  const int row_base = blockIdx.x * (NW * 4) + wave * 4;

  const float* Wp;
  if (row_base < b1)       Wp = W0 + (size_t)row_base * DIM;
  else if (row_base < b2)  Wp = W1 + (size_t)(row_base - b1) * DIM;
  else                     Wp = W2 + (size_t)(row_base - b2) * DIM;

  float acc[4][NB];
#pragma unroll
  for (int r = 0; r < 4; ++r)
#pragma unroll
    for (int b = 0; b < NB; ++b) acc[r][b] = 0.0f;

  for (int k0 = 0; k0 < DIM; k0 += 2048) {
    __syncthreads();
    // stage x[:, k0:k0+2048] -> LDS (8192 float4 across NW*64 threads)
#pragma unroll
    for (int i = 0; i < (8192 + NW * 64 - 1) / (NW * 64); ++i) {
      const int idx = tid + i * (NW * 64);
      if (idx < 8192) {
        const int b = idx >> 9, c = idx & 511;
        ((float4*)&xs[b][0])[c] =
            ((const float4*)(X + (size_t)b * DIM + k0))[c];
      }
    }
    __syncthreads();
#pragma unroll 4
    for (int ii = 0; ii < 8; ++ii) {
      const int d = ii * 256 + lane * 4;
      float4 w4[4];
#pragma unroll
      for (int r = 0; r < 4; ++r)
        w4[r] = *(const float4*)(Wp + (size_t)r * DIM + k0 + d);
#pragma unroll
      for (int b = 0; b < NB; ++b) {
        float4 x4 = *(const float4*)&xs[b][d];
#pragma unroll
        for (int r = 0; r < 4; ++r)
          acc[r][b] += w4[r].x * x4.x + w4[r].y * x4.y +
                       w4[r].z * x4.z + w4[r].w * x4.w;
      }
    }
  }

  // reduce each of the 64 (row,batch) partials across the 64 lanes
#pragma unroll
  for (int r = 0; r < 4; ++r)
#pragma unroll
    for (int b = 0; b < NB; ++b) {
      float v = acc[r][b];
#pragma unroll
      for (int m = 1; m < 64; m <<= 1) v += __shfl_xor(v, m);
      acc[r][b] = v;
    }
  const int rsel = lane >> 4, bsel = lane & 15;
  float v = 0.0f;
#pragma unroll
  for (int r = 0; r < 4; ++r)
#pragma unroll
    for (int b = 0; b < NB; ++b)
      if (r == rsel && b == bsel) v = acc[r][b];  // compile-time indices only
  const int row = row_base + rsel;
  if (row < scale_rows) v *= scale;
  Y[(size_t)bsel * y_stride + row] = v;
}

// ---------------------------------------------------------------------------
// Flash-decoding partial over the 8192 prefix keys only: one block per
// (b, kv-head g, 1024-key chunk) -> grid = 1024 blocks = exactly 4/CU.
// No masking anywhere. 256 threads = 4 waves; wave w scores keys
// [w*256, w*256+256) for all 4 q-heads, then wave h does softmax+PV for head h.
// ---------------------------------------------------------------------------
__global__ __launch_bounds__(256, 4) void attn_partial(
    const float* __restrict__ K, const float* __restrict__ V,
    const float* __restrict__ qkv, float* __restrict__ opart,
    float* __restrict__ mlpart) {
  __shared__ float sc[4 * CHUNK];  // 16 KB: scores, then p = exp(s-m)
  const int tid = threadIdx.x, wave = tid >> 6, lane = tid & 63;
  const int s = lane & 7, grp = lane >> 3;
  const int bid = blockIdx.x;
  const int chunk = bid & (NCHUNK - 1);
  const int bg = bid >> 3;
  const int g = bg & 7, b = bg >> 3;

  // q fragments in registers: lane covers dims {s*4 + j*32 + 0..3}
  float4 qreg[4][4];
#pragma unroll
  for (int hh = 0; hh < 4; ++hh)
#pragma unroll
    for (int j = 0; j < 4; ++j)
      qreg[hh][j] = *(const float4*)(qkv + (size_t)b * 6144 +
                                     (g * 4 + hh) * HD + j * 32 + s * 4);

  const int kbase = chunk * CHUNK + wave * 256;
  const float* krow0 = K + ((size_t)b * PREFIX * NKV + g) * HD +
                       (size_t)(kbase + grp) * (NKV * HD);

#pragma unroll 2
  for (int it = 0; it < 32; ++it) {
    const float* krow = krow0 + (size_t)it * 8 * (NKV * HD);
    float p0 = 0, p1 = 0, p2 = 0, p3 = 0;
#pragma unroll
    for (int j = 0; j < 4; ++j) {
      float4 k4 = *(const float4*)(krow + j * 32 + s * 4);
      p0 += qreg[0][j].x * k4.x + qreg[0][j].y * k4.y + qreg[0][j].z * k4.z + qreg[0][j].w * k4.w;
      p1 += qreg[1][j].x * k4.x + qreg[1][j].y * k4.y + qreg[1][j].z * k4.z + qreg[1][j].w * k4.w;
      p2 += qreg[2][j].x * k4.x + qreg[2][j].y * k4.y + qreg[2][j].z * k4.z + qreg[2][j].w * k4.w;
      p3 += qreg[3][j].x * k4.x + qreg[3][j].y * k4.y + qreg[3][j].z * k4.z + qreg[3][j].w * k4.w;
    }
    // reduce across the 8 lanes sharing this key
#pragma unroll
    for (int mk = 1; mk < 8; mk <<= 1) {
      p0 += __shfl_xor(p0, mk);
      p1 += __shfl_xor(p1, mk);
      p2 += __shfl_xor(p2, mk);
      p3 += __shfl_xor(p3, mk);
    }
    if (s == 0) {
      const int kl = wave * 256 + it * 8 + grp;
      sc[0 * CHUNK + kl] = p0;
      sc[1 * CHUNK + kl] = p1;
      sc[2 * CHUNK + kl] = p2;
      sc[3 * CHUNK + kl] = p3;
    }
  }
  __syncthreads();

  // per-head softmax over the 1024 chunk scores; wave h <-> head h.
  // Everything below is wave-local (no further barriers needed).
  const int h = wave;
  float* sch = &sc[h * CHUNK];
  float4 sv[4];
#pragma unroll
  for (int q = 0; q < 4; ++q) sv[q] = *(const float4*)&sch[q * 256 + lane * 4];
  float m = -1e30f;
#pragma unroll
  for (int q = 0; q < 4; ++q)
    m = fmaxf(m, fmaxf(fmaxf(sv[q].x, sv[q].y), fmaxf(sv[q].z, sv[q].w)));
#pragma unroll
  for (int mk = 1; mk < 64; mk <<= 1) m = fmaxf(m, __shfl_xor(m, mk));
  float lsum = 0.0f;
#pragma unroll
  for (int q = 0; q < 4; ++q) {
    sv[q].x = __expf(sv[q].x - m);
    sv[q].y = __expf(sv[q].y - m);
    sv[q].z = __expf(sv[q].z - m);
    sv[q].w = __expf(sv[q].w - m);
    lsum += sv[q].x + sv[q].y + sv[q].z + sv[q].w;
  }
#pragma unroll
  for (int mk = 1; mk < 64; mk <<= 1) lsum += __shfl_xor(lsum, mk);
#pragma unroll
  for (int q = 0; q < 4; ++q) *(float4*)&sch[q * 256 + lane * 4] = sv[q];

  // PV: half-wave kpar handles keys of parity kpar; lane covers 4 dims
  const int dgrp = lane & 31, kpar = lane >> 5;
  const int d0 = dgrp * 4;
  float4 acc = make_float4(0.f, 0.f, 0.f, 0.f);
  const float* vp = V + ((size_t)b * PREFIX * NKV + g) * HD + d0 +
                    (size_t)(chunk * CHUNK + kpar) * (NKV * HD);
#pragma unroll 8
  for (int kk = 0; kk < CHUNK; kk += 2) {
    const float p = sch[kk + kpar];
    float4 v4 = *(const float4*)(vp + (size_t)kk * (NKV * HD));
    acc.x += p * v4.x; acc.y += p * v4.y;
    acc.z += p * v4.z; acc.w += p * v4.w;
  }
  // merge the two key-parity halves
  acc.x += __shfl_xor(acc.x, 32);
  acc.y += __shfl_xor(acc.y, 32);
  acc.z += __shfl_xor(acc.z, 32);
  acc.w += __shfl_xor(acc.w, 32);
  const size_t pidx = (((size_t)(b * NKV + g)) * NCHUNK + chunk) * 4 + h;
  if (lane < 32) *(float4*)(opart + pidx * HD + d0) = acc;
  if (lane == 0) {
    mlpart[pidx * 2 + 0] = m;
    mlpart[pidx * 2 + 1] = lsum;
  }
}

// ---------------------------------------------------------------------------
// Combine the 8 chunk-partials per (b, head) AND fold in the new token
// analytically (its score is a single 128-dim dot). One wave per (b,h).
// ---------------------------------------------------------------------------
__global__ __launch_bounds__(64) void combine(
    const float* __restrict__ opart, const float* __restrict__ mlpart,
    const float* __restrict__ qkv, float* __restrict__ aout) {
  const int bh = blockIdx.x;  // b*32 + hg
  const int hg = bh & 31, b = bh >> 5;
  const int g = hg >> 2, hh = hg & 3;
  const int lane = threadIdx.x;
  const size_t base = ((size_t)(b * NKV + g)) * NCHUNK;

  // new-token score: q (already scaled) . k_new
  const float* qp = qkv + (size_t)b * 6144 + hg * HD;
  const float* kn = qkv + (size_t)b * 6144 + 4096 + g * HD;
  const float* vn = qkv + (size_t)b * 6144 + 5120 + g * HD;
  float2 q2 = *(const float2*)(qp + lane * 2);
  float2 k2 = *(const float2*)(kn + lane * 2);
  float sn = q2.x * k2.x + q2.y * k2.y;
#pragma unroll
  for (int mk = 1; mk < 64; mk <<= 1) sn += __shfl_xor(sn, mk);

  float M = sn;
#pragma unroll
  for (int c = 0; c < NCHUNK; ++c)
    M = fmaxf(M, mlpart[((base + c) * 4 + hh) * 2]);

  float L = 0, ax = 0, ay = 0;
#pragma unroll
  for (int c = 0; c < NCHUNK; ++c) {
    const size_t pidx = (base + c) * 4 + hh;
    const float mc = mlpart[pidx * 2 + 0];
    const float lc = mlpart[pidx * 2 + 1];
    const float w = __expf(mc - M);
    L += lc * w;
    float2 o2 = *(const float2*)(opart + pidx * HD + lane * 2);
    ax += w * o2.x;
    ay += w * o2.y;
  }
  const float pn = __expf(sn - M);
  float2 v2 = *(const float2*)(vn + lane * 2);
  L += pn;
  ax += pn * v2.x;
  ay += pn * v2.y;

  const float inv = 1.0f / L;
  aout[(size_t)b * DIM + hg * HD + lane * 2 + 0] = ax * inv;
  aout[(size_t)b * DIM + hg * HD + lane * 2 + 1] = ay * inv;
}

// ---------------------------------------------------------------------------
extern "C" void kernel_launch(void* const* d_in, const int* in_sizes, int n_in,
                              void* d_out, int out_size, void* d_ws,
                              size_t ws_size, hipStream_t stream) {
  const float* x  = (const float*)d_in[0];
  const float* ck = (const float*)d_in[1];
  const float* cv = (const float*)d_in[2];
  const float* wq = (const float*)d_in[3];
  const float* wk = (const float*)d_in[4];
  const float* wv = (const float*)d_in[5];
  const float* wo = (const float*)d_in[6];
  float* out = (float*)d_out;
  float* ws = (float*)d_ws;

  float* qkv = ws + WS_QKV;
  float* att = ws + WS_ATT;
  float* ml  = ws + WS_ML;
  float* op  = ws + WS_OP;

  const float scale = 0.08838834764831845f;  // 1/sqrt(128)

  // 1) fused q/k_new/v_new projection: 6144 rows = 24 rows x 256 blocks
  gemv16<6><<<256, 384, 0, stream>>>(wq, wk, wv, 4096, 5120, x, qkv, 6144,
                                     4096, scale);
  // 2) flash-decoding partials: exactly 1024 uniform blocks (4 per CU)
  attn_partial<<<NB * NKV * NCHUNK, 256, 0, stream>>>(ck, cv, qkv, op, ml);
  // 3) merge partials + new token
  combine<<<NB * NH, 64, 0, stream>>>(op, ml, qkv, att);
  // 4) output projection: 4096 rows = 16 rows x 256 blocks
  gemv16<4><<<256, 256, 0, stream>>>(wo, wo, wo, 4096, 4096, att, out, 4096,
                                     0, 1.0f);
}

// Round 4
// 272.723 us; speedup vs baseline: 1.4802x; 1.0651x over previous
//
#include <hip/hip_runtime.h>
#include <hip/hip_bf16.h>
#include <cstdint>
#include <cstddef>

#define DIM 4096
#define NB 16
#define NH 32
#define NKV 8
#define HD 128
#define PREFIX 8192
#define CHUNK 1024
#define NCHUNK 8      // 8 x 1024 = PREFIX; new token folded into combine
#define WKEYS 256     // keys per wave (CHUNK / 4 waves)
#define NPART (NCHUNK * 4)  // 32 wave-partials per (b,g)

// workspace layout (in floats)
#define WS_QKV 0                                    // [16][6144] q|k_new|v_new
#define WS_ATT (WS_QKV + NB * 6144)                 // [16][4096] attn output
#define WS_ML  (WS_ATT + NB * DIM)                  // [16*8*32][4][2]
#define WS_OP  (WS_ML + NB * NKV * NPART * 4 * 2)   // [16*8*32][4][128]

// ---------------------------------------------------------------------------
// Batched GEMV: Y[b][row] = sum_d X[b][d] * W[row][d], B=16, D=4096.
// W = concat of up to three row-major matrices (boundaries b1,b2).
// NW waves per block; each wave owns 4 rows x 16 batches. x staged in two
// 2048-dim chunks (128 KB LDS) -> only 2 barrier pairs per block.
// ---------------------------------------------------------------------------
template <int NW>
__global__ __launch_bounds__(NW * 64) void gemv16(
    const float* __restrict__ W0, const float* __restrict__ W1,
    const float* __restrict__ W2, int b1, int b2,
    const float* __restrict__ X, float* __restrict__ Y,
    int y_stride, int scale_rows, float scale) {
  __shared__ float xs[NB][2048];  // 128 KB
  const int tid = threadIdx.x;
  const int wave = tid >> 6, lane = tid & 63;
  const int row_base = blockIdx.x * (NW * 4) + wave * 4;

  const float* Wp;
  if (row_base < b1)       Wp = W0 + (size_t)row_base * DIM;
  else if (row_base < b2)  Wp = W1 + (size_t)(row_base - b1) * DIM;
  else                     Wp = W2 + (size_t)(row_base - b2) * DIM;

  float acc[4][NB];
#pragma unroll
  for (int r = 0; r < 4; ++r)
#pragma unroll
    for (int b = 0; b < NB; ++b) acc[r][b] = 0.0f;

  for (int k0 = 0; k0 < DIM; k0 += 2048) {
    __syncthreads();
    // stage x[:, k0:k0+2048] -> LDS (8192 float4 across NW*64 threads)
#pragma unroll
    for (int i = 0; i < (8192 + NW * 64 - 1) / (NW * 64); ++i) {
      const int idx = tid + i * (NW * 64);
      if (idx < 8192) {
        const int b = idx >> 9, c = idx & 511;
        ((float4*)&xs[b][0])[c] =
            ((const float4*)(X + (size_t)b * DIM + k0))[c];
      }
    }
    __syncthreads();
#pragma unroll 4
    for (int ii = 0; ii < 8; ++ii) {
      const int d = ii * 256 + lane * 4;
      float4 w4[4];
#pragma unroll
      for (int r = 0; r < 4; ++r)
        w4[r] = *(const float4*)(Wp + (size_t)r * DIM + k0 + d);
#pragma unroll
      for (int b = 0; b < NB; ++b) {
        float4 x4 = *(const float4*)&xs[b][d];
#pragma unroll
        for (int r = 0; r < 4; ++r)
          acc[r][b] += w4[r].x * x4.x + w4[r].y * x4.y +
                       w4[r].z * x4.z + w4[r].w * x4.w;
      }
    }
  }

  // reduce each of the 64 (row,batch) partials across the 64 lanes
#pragma unroll
  for (int r = 0; r < 4; ++r)
#pragma unroll
    for (int b = 0; b < NB; ++b) {
      float v = acc[r][b];
#pragma unroll
      for (int m = 1; m < 64; m <<= 1) v += __shfl_xor(v, m);
      acc[r][b] = v;
    }
  const int rsel = lane >> 4, bsel = lane & 15;
  float v = 0.0f;
#pragma unroll
  for (int r = 0; r < 4; ++r)
#pragma unroll
    for (int b = 0; b < NB; ++b)
      if (r == rsel && b == bsel) v = acc[r][b];  // compile-time indices only
  const int row = row_base + rsel;
  if (row < scale_rows) v *= scale;
  Y[(size_t)bsel * y_stride + row] = v;
}

// ---------------------------------------------------------------------------
// Wave-independent flash-decoding partial. Block = (b, g, 1024-key chunk),
// 4 waves; wave w owns keys [w*256, w*256+256) and does score -> wave-local
// softmax -> PV for all 4 q-heads of the group. NO block barriers; V bytes
// read exactly once. Each wave emits its own (o, m, l) partial.
// ---------------------------------------------------------------------------
__global__ __launch_bounds__(256, 4) void attn_partial(
    const float* __restrict__ K, const float* __restrict__ V,
    const float* __restrict__ qkv, float* __restrict__ opart,
    float* __restrict__ mlpart) {
  __shared__ float sc[4][4 * WKEYS];  // 16 KB, per-wave private regions
  const int tid = threadIdx.x, wave = tid >> 6, lane = tid & 63;
  const int s = lane & 7, grp = lane >> 3;
  const int bid = blockIdx.x;
  const int chunk = bid & (NCHUNK - 1);
  const int bg = bid >> 3;
  const int g = bg & 7, b = bg >> 3;
  float* scw = &sc[wave][0];

  // q fragments in registers: lane covers dims {s*4 + j*32 + 0..3}
  float4 qreg[4][4];
#pragma unroll
  for (int hh = 0; hh < 4; ++hh)
#pragma unroll
    for (int j = 0; j < 4; ++j)
      qreg[hh][j] = *(const float4*)(qkv + (size_t)b * 6144 +
                                     (g * 4 + hh) * HD + j * 32 + s * 4);

  const int kbase = chunk * CHUNK + wave * WKEYS;
  const float* krow0 = K + ((size_t)b * PREFIX * NKV + g) * HD +
                       (size_t)(kbase + grp) * (NKV * HD);

  // ---- scoring: 32 iterations x 8 keys ----
#pragma unroll 2
  for (int it = 0; it < 32; ++it) {
    const float* krow = krow0 + (size_t)it * 8 * (NKV * HD);
    float p0 = 0, p1 = 0, p2 = 0, p3 = 0;
#pragma unroll
    for (int j = 0; j < 4; ++j) {
      float4 k4 = *(const float4*)(krow + j * 32 + s * 4);
      p0 += qreg[0][j].x * k4.x + qreg[0][j].y * k4.y + qreg[0][j].z * k4.z + qreg[0][j].w * k4.w;
      p1 += qreg[1][j].x * k4.x + qreg[1][j].y * k4.y + qreg[1][j].z * k4.z + qreg[1][j].w * k4.w;
      p2 += qreg[2][j].x * k4.x + qreg[2][j].y * k4.y + qreg[2][j].z * k4.z + qreg[2][j].w * k4.w;
      p3 += qreg[3][j].x * k4.x + qreg[3][j].y * k4.y + qreg[3][j].z * k4.z + qreg[3][j].w * k4.w;
    }
    // reduce across the 8 lanes sharing this key
#pragma unroll
    for (int mk = 1; mk < 8; mk <<= 1) {
      p0 += __shfl_xor(p0, mk);
      p1 += __shfl_xor(p1, mk);
      p2 += __shfl_xor(p2, mk);
      p3 += __shfl_xor(p3, mk);
    }
    if (s == 0) {
      const int kl = it * 8 + grp;
      scw[0 * WKEYS + kl] = p0;
      scw[1 * WKEYS + kl] = p1;
      scw[2 * WKEYS + kl] = p2;
      scw[3 * WKEYS + kl] = p3;
    }
  }
  // drain LDS writes so all lanes of this wave see them (no block barrier)
  asm volatile("s_waitcnt lgkmcnt(0)" ::: "memory");
  __builtin_amdgcn_sched_barrier(0);

  // ---- wave-local softmax per head over this wave's 256 keys ----
  float m_h[4], l_h[4];
#pragma unroll
  for (int hh = 0; hh < 4; ++hh) {
    float4 sv = *(const float4*)&scw[hh * WKEYS + lane * 4];
    float m = fmaxf(fmaxf(sv.x, sv.y), fmaxf(sv.z, sv.w));
#pragma unroll
    for (int mk = 1; mk < 64; mk <<= 1) m = fmaxf(m, __shfl_xor(m, mk));
    float4 pv;
    pv.x = __expf(sv.x - m);
    pv.y = __expf(sv.y - m);
    pv.z = __expf(sv.z - m);
    pv.w = __expf(sv.w - m);
    float l = pv.x + pv.y + pv.z + pv.w;
#pragma unroll
    for (int mk = 1; mk < 64; mk <<= 1) l += __shfl_xor(l, mk);
    *(float4*)&scw[hh * WKEYS + lane * 4] = pv;
    m_h[hh] = m;
    l_h[hh] = l;
  }
  asm volatile("s_waitcnt lgkmcnt(0)" ::: "memory");
  __builtin_amdgcn_sched_barrier(0);

  // ---- PV over this wave's 256 keys, all 4 heads ----
  const int dgrp = lane & 31, kpar = lane >> 5;
  const int d0 = dgrp * 4;
  float4 acc[4];
#pragma unroll
  for (int hh = 0; hh < 4; ++hh) acc[hh] = make_float4(0.f, 0.f, 0.f, 0.f);
  const float* vp = V + ((size_t)b * PREFIX * NKV + g) * HD + d0 +
                    (size_t)(kbase + kpar) * (NKV * HD);
#pragma unroll 4
  for (int kk = 0; kk < WKEYS; kk += 2) {
    float4 v4 = *(const float4*)(vp + (size_t)kk * (NKV * HD));
#pragma unroll
    for (int hh = 0; hh < 4; ++hh) {
      const float p = scw[hh * WKEYS + kk + kpar];
      acc[hh].x += p * v4.x;
      acc[hh].y += p * v4.y;
      acc[hh].z += p * v4.z;
      acc[hh].w += p * v4.w;
    }
  }
  // merge the two key-parity halves
#pragma unroll
  for (int hh = 0; hh < 4; ++hh) {
    acc[hh].x += __shfl_xor(acc[hh].x, 32);
    acc[hh].y += __shfl_xor(acc[hh].y, 32);
    acc[hh].z += __shfl_xor(acc[hh].z, 32);
    acc[hh].w += __shfl_xor(acc[hh].w, 32);
  }
  const size_t pp = (((size_t)(b * NKV + g)) * NCHUNK + chunk) * 4 + wave;
  if (lane < 32) {
#pragma unroll
    for (int hh = 0; hh < 4; ++hh)
      *(float4*)(opart + (pp * 4 + hh) * HD + d0) = acc[hh];
  }
  if (lane == 0) {
#pragma unroll
    for (int hh = 0; hh < 4; ++hh) {
      mlpart[(pp * 4 + hh) * 2 + 0] = m_h[hh];
      mlpart[(pp * 4 + hh) * 2 + 1] = l_h[hh];
    }
  }
}

// ---------------------------------------------------------------------------
// Combine the 32 wave-partials per (b, head) AND fold in the new token
// analytically (its score is a single 128-dim dot). One wave per (b,h).
// ---------------------------------------------------------------------------
__global__ __launch_bounds__(64) void combine(
    const float* __restrict__ opart, const float* __restrict__ mlpart,
    const float* __restrict__ qkv, float* __restrict__ aout) {
  const int bh = blockIdx.x;  // b*32 + hg
  const int hg = bh & 31, b = bh >> 5;
  const int g = hg >> 2, hh = hg & 3;
  const int lane = threadIdx.x;
  // flat partial index for (b,g,chunk,wave,head): base + c*4 + hh, c=0..31
  const size_t base = (size_t)(b * NKV + g) * (NPART * 4) + hh;

  // new-token score: q (already scaled) . k_new
  const float* qp = qkv + (size_t)b * 6144 + hg * HD;
  const float* kn = qkv + (size_t)b * 6144 + 4096 + g * HD;
  const float* vn = qkv + (size_t)b * 6144 + 5120 + g * HD;
  float2 q2 = *(const float2*)(qp + lane * 2);
  float2 k2 = *(const float2*)(kn + lane * 2);
  float sn = q2.x * k2.x + q2.y * k2.y;
#pragma unroll
  for (int mk = 1; mk < 64; mk <<= 1) sn += __shfl_xor(sn, mk);

  float M = sn;
#pragma unroll 8
  for (int c = 0; c < NPART; ++c)
    M = fmaxf(M, mlpart[(base + c * 4) * 2]);

  float L = 0, ax = 0, ay = 0;
#pragma unroll 8
  for (int c = 0; c < NPART; ++c) {
    const size_t pidx = base + c * 4;
    const float mc = mlpart[pidx * 2 + 0];
    const float lc = mlpart[pidx * 2 + 1];
    const float w = __expf(mc - M);
    L += lc * w;
    float2 o2 = *(const float2*)(opart + pidx * HD + lane * 2);
    ax += w * o2.x;
    ay += w * o2.y;
  }
  const float pn = __expf(sn - M);
  float2 v2 = *(const float2*)(vn + lane * 2);
  L += pn;
  ax += pn * v2.x;
  ay += pn * v2.y;

  const float inv = 1.0f / L;
  aout[(size_t)b * DIM + hg * HD + lane * 2 + 0] = ax * inv;
  aout[(size_t)b * DIM + hg * HD + lane * 2 + 1] = ay * inv;
}

// ---------------------------------------------------------------------------
extern "C" void kernel_launch(void* const* d_in, const int* in_sizes, int n_in,
                              void* d_out, int out_size, void* d_ws,
                              size_t ws_size, hipStream_t stream) {
  const float* x  = (const float*)d_in[0];
  const float* ck = (const float*)d_in[1];
  const float* cv = (const float*)d_in[2];
  const float* wq = (const float*)d_in[3];
  const float* wk = (const float*)d_in[4];
  const float* wv = (const float*)d_in[5];
  const float* wo = (const float*)d_in[6];
  float* out = (float*)d_out;
  float* ws = (float*)d_ws;

  float* qkv = ws + WS_QKV;
  float* att = ws + WS_ATT;
  float* ml  = ws + WS_ML;
  float* op  = ws + WS_OP;

  const float scale = 0.08838834764831845f;  // 1/sqrt(128)

  // 1) fused q/k_new/v_new projection: 6144 rows = 24 rows x 256 blocks
  gemv16<6><<<256, 384, 0, stream>>>(wq, wk, wv, 4096, 5120, x, qkv, 6144,
                                     4096, scale);
  // 2) flash-decoding partials: 1024 uniform blocks, wave-independent
  attn_partial<<<NB * NKV * NCHUNK, 256, 0, stream>>>(ck, cv, qkv, op, ml);
  // 3) merge 32 partials per (b,h) + new token
  combine<<<NB * NH, 64, 0, stream>>>(op, ml, qkv, att);
  // 4) output projection: 4096 rows = 16 rows x 256 blocks
  gemv16<4><<<256, 256, 0, stream>>>(wo, wo, wo, 4096, 4096, att, out, 4096,
                                     0, 1.0f);
}